// Round 6
// baseline (2370.740 us; speedup 1.0000x reference)
//
#include <hip/hip_runtime.h>
#include <hip/hip_bf16.h>

typedef short bf16x8 __attribute__((ext_vector_type(8)));
typedef float f32x4 __attribute__((ext_vector_type(4)));

#define NN 131072
#define BM 64
#define LDW 520    // 512 + 8 pad cols (1040B row stride -> conflict-free ds_read_b128)
#define LDSS 136   // 128 + 8 pad cols

// WT (transposed bf16 weights) element offsets in d_ws
#define OFF_LD 0
#define OFF_RD 8192
#define OFF_FD 106496
#define OFF_C1 237568
#define OFF_C2 303104
#define OFF_C3 368640
#define OFF_CD 434176
#define OFF_CN 441088
#define OFF_ND 473856
#define OFF_N1 604928
#define OFF_N2 867072
#define OFF_A0 1129216
#define OFF_A1 1653504
#define OFF_N3 2177792
#define WT_TOTAL 2229504

__device__ __forceinline__ unsigned short f2b(float f) {
  __hip_bfloat16 h = __float2bfloat16(f);
  return __builtin_bit_cast(unsigned short, h);
}
__device__ __forceinline__ float b2f(unsigned short u) {
  return __bfloat162float(__builtin_bit_cast(__hip_bfloat16, u));
}

template<int Kd, int Md>
__device__ __forceinline__ unsigned short convT(int local, const float* __restrict__ W) {
  int mm = local / Kd;          // output col (row of WT)
  int kk = local - mm * Kd;     // k
  return f2b(W[(size_t)kk * Md + mm]);
}

__global__ void prep_weights(const float* __restrict__ Wld, const float* __restrict__ Wrd,
                             const float* __restrict__ Wfd, const float* __restrict__ Wc1,
                             const float* __restrict__ Wc2, const float* __restrict__ Wc3,
                             const float* __restrict__ Wcd, const float* __restrict__ Wcn,
                             const float* __restrict__ Wnd, const float* __restrict__ Wn1,
                             const float* __restrict__ Wn2, const float* __restrict__ Wa0,
                             const float* __restrict__ Wa1, const float* __restrict__ Wn3,
                             unsigned short* __restrict__ WT) {
  int e = blockIdx.x * 256 + threadIdx.x;
  unsigned short r;
  if      (e < OFF_RD) r = convT<64, 128>(e - OFF_LD, Wld);
  else if (e < OFF_FD) r = convT<128, 768>(e - OFF_RD, Wrd);
  else if (e < OFF_C1) r = convT<256, 512>(e - OFF_FD, Wfd);
  else if (e < OFF_C2) r = convT<256, 256>(e - OFF_C1, Wc1);
  else if (e < OFF_C3) r = convT<256, 256>(e - OFF_C2, Wc2);
  else if (e < OFF_CD) r = convT<256, 256>(e - OFF_C3, Wc3);
  else if (e < OFF_CN) r = convT<256, 27>(e - OFF_CD, Wcd);
  else if (e < OFF_ND) r = convT<128, 256>(e - OFF_CN, Wcn);
  else if (e < OFF_N1) r = convT<256, 512>(e - OFF_ND, Wnd);
  else if (e < OFF_N2) r = convT<512, 512>(e - OFF_N1, Wn1);
  else if (e < OFF_A0) r = convT<512, 512>(e - OFF_N2, Wn2);
  else if (e < OFF_A1) r = convT<512, 1024>(e - OFF_A0, Wa0);
  else if (e < OFF_N3) r = convT<1024, 512>(e - OFF_A1, Wa1);
  else                 r = convT<512, 101>(e - OFF_N3, Wn3);
  WT[e] = r;
}

// Pipelined GEMM layer, 16-wave version: wave = (rh = wid&1 row-half, cg = wid>>1
// col-group). Each wave computes 32 rows (rh*32..) x GSIZE*16 cols per group.
// A in padded LDS, B streamed from WT. PB = B-prefetch depth (k-steps).
// Full unroll folds k-offsets into load immediates.
// ACT: 0=relu, 1=sigmoid(x), 2=sigmoid(2x).
template<int K, int NOUT, int GSIZE, int PB, int ACT, bool TO_GLOBAL, bool ADD>
__device__ __forceinline__ void layer(
    const unsigned short* __restrict__ Ain, int lda,
    const unsigned short* __restrict__ Bw,
    const float* __restrict__ bias,
    unsigned short* __restrict__ Lout, int ldo,
    float* __restrict__ Gout, int gld,
    const unsigned short* __restrict__ Aadd, int ldadd,
    int lane, int wid) {
  constexpr int NT = (NOUT + 15) >> 4;
  constexpr int NG = (NT + GSIZE - 1) / GSIZE;
  const int cg = wid >> 1;
  const int rh = wid & 1;
  const int l15 = lane & 15;
  const int quad = lane >> 4;
  const int kh = quad << 3;
  const int rbase = rh * 32;
  for (int g = cg; g < NG; g += 8) {
    f32x4 acc[2][GSIZE] = {};
    const unsigned short* bp[GSIZE];
    int cols[GSIZE];
    #pragma unroll
    for (int t = 0; t < GSIZE; ++t) {
      int col = (g * GSIZE + t) * 16 + l15;
      cols[t] = col;
      int cc = col < NOUT ? col : NOUT - 1;   // clamp pad cols (safe dup work)
      bp[t] = Bw + (size_t)cc * K + kh;
    }
    const unsigned short* ap[2];
    #pragma unroll
    for (int m = 0; m < 2; ++m) ap[m] = Ain + (rbase + m * 16 + l15) * lda + kh;
    // prologue
    bf16x8 bc[GSIZE], b1[GSIZE], ac[2];
    #pragma unroll
    for (int t = 0; t < GSIZE; ++t) bc[t] = *(const bf16x8*)(bp[t]);
    if constexpr (PB >= 2) {
      #pragma unroll
      for (int t = 0; t < GSIZE; ++t) b1[t] = *(const bf16x8*)(bp[t] + 32);
    }
    #pragma unroll
    for (int m = 0; m < 2; ++m) ac[m] = *(const bf16x8*)(ap[m]);
    #pragma unroll
    for (int k0 = 0; k0 < K; k0 += 32) {
      bf16x8 bn[GSIZE], an[2];
      if (k0 + PB * 32 < K) {
        #pragma unroll
        for (int t = 0; t < GSIZE; ++t) bn[t] = *(const bf16x8*)(bp[t] + k0 + PB * 32);
      }
      if (k0 + 32 < K) {
        #pragma unroll
        for (int m = 0; m < 2; ++m) an[m] = *(const bf16x8*)(ap[m] + k0 + 32);
      }
      #pragma unroll
      for (int m = 0; m < 2; ++m) {
        #pragma unroll
        for (int t = 0; t < GSIZE; ++t)
          acc[m][t] = __builtin_amdgcn_mfma_f32_16x16x32_bf16(ac[m], bc[t], acc[m][t], 0, 0, 0);
      }
      if (k0 + 32 < K) {
        #pragma unroll
        for (int m = 0; m < 2; ++m) ac[m] = an[m];
        if constexpr (PB >= 2) {
          #pragma unroll
          for (int t = 0; t < GSIZE; ++t) bc[t] = b1[t];
          if (k0 + 64 < K) {
            #pragma unroll
            for (int t = 0; t < GSIZE; ++t) b1[t] = bn[t];
          }
        } else {
          #pragma unroll
          for (int t = 0; t < GSIZE; ++t) bc[t] = bn[t];
        }
      }
    }
    // epilogue
    #pragma unroll
    for (int t = 0; t < GSIZE; ++t) {
      int cc = cols[t] < NOUT ? cols[t] : NOUT - 1;
      float bb = bias[cc];
      #pragma unroll
      for (int m = 0; m < 2; ++m) {
        #pragma unroll
        for (int j = 0; j < 4; ++j) {
          int row = rbase + m * 16 + quad * 4 + j;
          float v = acc[m][t][j] + bb;
          if constexpr (ACT == 0) v = fmaxf(v, 0.f);
          else if constexpr (ACT == 1) v = 1.f / (1.f + __expf(-v));
          else if constexpr (ACT == 2) v = 1.f / (1.f + __expf(-2.f * v));
          if constexpr (ADD) v += b2f(Aadd[row * ldadd + cols[t]]);
          if constexpr (TO_GLOBAL) {
            if (cols[t] < NOUT) Gout[(size_t)row * gld + cols[t]] = v;
          } else {
            Lout[row * ldo + cols[t]] = f2b(v);
          }
        }
      }
    }
  }
}

// 1024 threads = 16 waves = 4 waves/SIMD (forced residency on one CU).
// min-waves/EU = 4 -> VGPR cap 512/4 = 128/wave, which this code is sized for.
__global__ __launch_bounds__(1024, 4)
void fused_vae(const float* __restrict__ z, const int* __restrict__ cind,
               const float* __restrict__ Emb,
               const float* __restrict__ bld, const float* __restrict__ brd,
               const float* __restrict__ bfd, const float* __restrict__ bc1,
               const float* __restrict__ bc2, const float* __restrict__ bc3,
               const float* __restrict__ bcd, const float* __restrict__ bcn,
               const float* __restrict__ bnd, const float* __restrict__ bn1,
               const float* __restrict__ bn2, const float* __restrict__ ba0,
               const float* __restrict__ ba1, const float* __restrict__ bn3,
               const unsigned short* __restrict__ WT, float* __restrict__ out) {
  __shared__ unsigned short sS[BM * LDSS];
  __shared__ unsigned short sA[BM * LDW];
  __shared__ unsigned short sB[BM * LDW];
  const int tid = threadIdx.x;
  const int lane = tid & 63;
  const int wid = tid >> 6;      // 0..15
  const size_t row0 = (size_t)blockIdx.x * BM;

  // stage z tile -> sA (bf16): 4096 elems, one pass at 1024 threads x4
  for (int e = tid * 4; e < BM * 64; e += 1024 * 4) {
    int r = e >> 6, c = e & 63;
    float4 v = *(const float4*)(z + (row0 + r) * 64 + c);
    ushort4 u; u.x = f2b(v.x); u.y = f2b(v.y); u.z = f2b(v.z); u.w = f2b(v.w);
    *(ushort4*)(&sA[r * LDW + c]) = u;
  }
  __syncthreads();
  // z1 = relu(z @ Wld + bld) -> sS [64][128]
  layer<64, 128, 1, 2, 0, false, false>(sA, LDW, WT + OFF_LD, bld, sS, LDSS, nullptr, 0, nullptr, 0, lane, wid);
  __syncthreads();
  // cl_h = relu(z1 @ Wrd[:,512:768] + brd[512:]) -> sB
  layer<128, 256, 2, 2, 0, false, false>(sS, LDSS, WT + OFF_RD + 512 * 128, brd + 512, sB, LDW, nullptr, 0, nullptr, 0, lane, wid);
  __syncthreads();
  layer<256, 256, 2, 2, 0, false, false>(sB, LDW, WT + OFF_C1, bc1, sA, LDW, nullptr, 0, nullptr, 0, lane, wid);
  __syncthreads();
  layer<256, 256, 2, 2, 0, false, false>(sA, LDW, WT + OFF_C2, bc2, sB, LDW, nullptr, 0, nullptr, 0, lane, wid);
  __syncthreads();
  layer<256, 256, 2, 2, 0, false, false>(sB, LDW, WT + OFF_C3, bc3, sA, LDW, nullptr, 0, nullptr, 0, lane, wid);
  __syncthreads();
  // cluster = sigmoid(2*(c3 @ Wcd + bcd)) -> global (cg 0-1 only)
  // || feat_h = relu(z1 @ Wrd[:,0:256]) -> sB (reads sS; disjoint from CD's sA)
  layer<256, 27, 1, 2, 2, true, false>(sA, LDW, WT + OFF_CD, bcd, nullptr, 0,
                                       out + (size_t)NN * 613 + row0 * 27, 27, nullptr, 0, lane, wid);
  layer<128, 256, 2, 2, 0, false, false>(sS, LDSS, WT + OFF_RD, brd, sB, LDW, nullptr, 0, nullptr, 0, lane, wid);
  __syncthreads();
  // feat = sigmoid(feat_h @ Wfd + bfd) -> global  ||  nb_h -> sA (reads sS)
  layer<256, 512, 4, 1, 1, true, false>(sB, LDW, WT + OFF_FD, bfd, nullptr, 0,
                                        out + row0 * 512, 512, nullptr, 0, lane, wid);
  layer<128, 256, 2, 2, 0, false, false>(sS, LDSS, WT + OFF_RD + 256 * 128, brd + 256, sA, LDW, nullptr, 0, nullptr, 0, lane, wid);
  __syncthreads();
  // stage emb = Emb[cluster_ind] -> sS (z1 dead): 8192 elems, two passes
  for (int e = tid * 4; e < BM * 128; e += 1024 * 4) {
    int r = e >> 7, c = e & 127;
    int ci = cind[row0 + r];
    float4 v = *(const float4*)(Emb + (size_t)ci * 128 + c);
    ushort4 u; u.x = f2b(v.x); u.y = f2b(v.y); u.z = f2b(v.z); u.w = f2b(v.w);
    *(ushort4*)(&sS[r * LDSS + c]) = u;
  }
  __syncthreads();
  // x = relu(emb @ Wcn + bcn) + nb_h -> sB (ADD reads sA)
  layer<128, 256, 2, 2, 0, false, true>(sS, LDSS, WT + OFF_CN, bcn, sB, LDW, nullptr, 0, sA, LDW, lane, wid);
  __syncthreads();
  // nf1 -> sA
  layer<256, 512, 4, 1, 0, false, false>(sB, LDW, WT + OFF_ND, bnd, sA, LDW, nullptr, 0, nullptr, 0, lane, wid);
  __syncthreads();
  // nf2 -> sB
  layer<512, 512, 4, 1, 0, false, false>(sA, LDW, WT + OFF_N1, bn1, sB, LDW, nullptr, 0, nullptr, 0, lane, wid);
  __syncthreads();
  // nf3 -> sA
  layer<512, 512, 4, 1, 0, false, false>(sB, LDW, WT + OFF_N2, bn2, sA, LDW, nullptr, 0, nullptr, 0, lane, wid);
  __syncthreads();
  // a0 (1024-wide, two 512 halves through sB) fused with a1 accumulation in regs.
  // acc1 (32 regs) lives across the a0 layer call (GSIZE=2 there to cap pressure).
  {
    const int cg = wid >> 1;
    const int rh = wid & 1;
    const int l15 = lane & 15;
    const int quad = lane >> 4;
    const int kh = quad << 3;
    const int rbase = rh * 32;
    f32x4 acc1[2][4] = {};
    for (int h = 0; h < 2; ++h) {
      layer<512, 512, 2, 1, 0, false, false>(sA, LDW, WT + OFF_A0 + (size_t)h * 512 * 512,
                                             ba0 + h * 512, sB, LDW, nullptr, 0, nullptr, 0, lane, wid);
      __syncthreads();
      const unsigned short* wa1 = WT + OFF_A1 + h * 512;   // [512][1024], k-offset h*512
      const unsigned short* bp[4];
      #pragma unroll
      for (int t = 0; t < 4; ++t)
        bp[t] = wa1 + (size_t)(cg * 64 + t * 16 + l15) * 1024 + kh;
      const unsigned short* ap[2];
      #pragma unroll
      for (int m = 0; m < 2; ++m) ap[m] = sB + (rbase + m * 16 + l15) * LDW + kh;
      // PB=1 pipeline over K=512
      bf16x8 bc[4], ac[2];
      #pragma unroll
      for (int t = 0; t < 4; ++t) bc[t] = *(const bf16x8*)(bp[t]);
      #pragma unroll
      for (int m = 0; m < 2; ++m) ac[m] = *(const bf16x8*)(ap[m]);
      #pragma unroll
      for (int k0 = 0; k0 < 512; k0 += 32) {
        bf16x8 bn[4], an[2];
        if (k0 + 32 < 512) {
          #pragma unroll
          for (int t = 0; t < 4; ++t) bn[t] = *(const bf16x8*)(bp[t] + k0 + 32);
          #pragma unroll
          for (int m = 0; m < 2; ++m) an[m] = *(const bf16x8*)(ap[m] + k0 + 32);
        }
        #pragma unroll
        for (int m = 0; m < 2; ++m) {
          #pragma unroll
          for (int t = 0; t < 4; ++t)
            acc1[m][t] = __builtin_amdgcn_mfma_f32_16x16x32_bf16(ac[m], bc[t], acc1[m][t], 0, 0, 0);
        }
        if (k0 + 32 < 512) {
          #pragma unroll
          for (int t = 0; t < 4; ++t) bc[t] = bn[t];
          #pragma unroll
          for (int m = 0; m < 2; ++m) ac[m] = an[m];
        }
      }
      __syncthreads();
    }
    // a1 = relu(acc1 + ba1) -> sB (rows rbase..+31, cols cg*64..+63; disjoint)
    #pragma unroll
    for (int t = 0; t < 4; ++t) {
      int col = cg * 64 + t * 16 + l15;
      float bb = ba1[col];
      #pragma unroll
      for (int m = 0; m < 2; ++m) {
        #pragma unroll
        for (int j = 0; j < 4; ++j) {
          int row = rbase + m * 16 + quad * 4 + j;
          sB[row * LDW + col] = f2b(fmaxf(acc1[m][t][j] + bb, 0.f));
        }
      }
    }
  }
  __syncthreads();
  // neighbor_map = sigmoid(2*(a1 @ Wn3 + bn3)) -> global
  layer<512, 101, 1, 2, 2, true, false>(sB, LDW, WT + OFF_N3, bn3, nullptr, 0,
                                        out + (size_t)NN * 512 + row0 * 101, 101, nullptr, 0, lane, wid);
}

extern "C" void kernel_launch(void* const* d_in, const int* in_sizes, int n_in,
                              void* d_out, int out_size, void* d_ws, size_t ws_size,
                              hipStream_t stream) {
  const float* z   = (const float*)d_in[0];
  const int*   cind= (const int*)d_in[1];
  const float* Emb = (const float*)d_in[2];
  const float* Wld = (const float*)d_in[3];  const float* bld = (const float*)d_in[4];
  const float* Wrd = (const float*)d_in[5];  const float* brd = (const float*)d_in[6];
  const float* Wfd = (const float*)d_in[7];  const float* bfd = (const float*)d_in[8];
  const float* Wc1 = (const float*)d_in[9];  const float* bc1 = (const float*)d_in[10];
  const float* Wc2 = (const float*)d_in[11]; const float* bc2 = (const float*)d_in[12];
  const float* Wc3 = (const float*)d_in[13]; const float* bc3 = (const float*)d_in[14];
  const float* Wcd = (const float*)d_in[15]; const float* bcd = (const float*)d_in[16];
  const float* Wcn = (const float*)d_in[17]; const float* bcn = (const float*)d_in[18];
  const float* Wnd = (const float*)d_in[19]; const float* bnd = (const float*)d_in[20];
  const float* Wn1 = (const float*)d_in[21]; const float* bn1 = (const float*)d_in[22];
  const float* Wn2 = (const float*)d_in[23]; const float* bn2 = (const float*)d_in[24];
  const float* Wa0 = (const float*)d_in[25]; const float* ba0 = (const float*)d_in[26];
  const float* Wa1 = (const float*)d_in[27]; const float* ba1 = (const float*)d_in[28];
  const float* Wn3 = (const float*)d_in[29]; const float* bn3 = (const float*)d_in[30];
  unsigned short* WT = (unsigned short*)d_ws;
  float* out = (float*)d_out;

  prep_weights<<<WT_TOTAL / 256, 256, 0, stream>>>(Wld, Wrd, Wfd, Wc1, Wc2, Wc3, Wcd,
                                                   Wcn, Wnd, Wn1, Wn2, Wa0, Wa1, Wn3, WT);
  fused_vae<<<NN / BM, 1024, 0, stream>>>(z, cind, Emb, bld, brd, bfd, bc1, bc2, bc3,
                                          bcd, bcn, bnd, bn1, bn2, ba0, ba1, bn3, WT, out);
}

// Round 7
// 1541.647 us; speedup vs baseline: 1.5378x; 1.5378x over previous
//
#include <hip/hip_runtime.h>
#include <hip/hip_bf16.h>

typedef short bf16x8 __attribute__((ext_vector_type(8)));
typedef float f32x4 __attribute__((ext_vector_type(4)));

#define NN 131072
#define BM 64
#define WRS 512   // Wb row stride (elems); XOR swizzle handles banks
#define SRS 128   // Sb row stride

// WT (transposed bf16 weights) element offsets in d_ws (row length == layer K)
#define OFF_LD 0
#define OFF_RD 8192
#define OFF_FD 106496
#define OFF_C1 237568
#define OFF_C2 303104
#define OFF_C3 368640
#define OFF_CD 434176
#define OFF_CN 441088
#define OFF_ND 473856
#define OFF_N1 604928
#define OFF_N2 867072
#define OFF_A0 1129216
#define OFF_A1 1653504
#define OFF_N3 2177792
#define WT_TOTAL 2229504

__device__ __forceinline__ unsigned short f2b(float f) {
  __hip_bfloat16 h = __float2bfloat16(f);
  return __builtin_bit_cast(unsigned short, h);
}
__device__ __forceinline__ float b2f(unsigned short u) {
  return __bfloat162float(__builtin_bit_cast(__hip_bfloat16, u));
}

template<int Kd, int Md>
__device__ __forceinline__ unsigned short convT(int local, const float* __restrict__ W) {
  int mm = local / Kd;          // output col (row of WT)
  int kk = local - mm * Kd;     // k
  return f2b(W[(size_t)kk * Md + mm]);
}

__global__ void prep_weights(const float* __restrict__ Wld, const float* __restrict__ Wrd,
                             const float* __restrict__ Wfd, const float* __restrict__ Wc1,
                             const float* __restrict__ Wc2, const float* __restrict__ Wc3,
                             const float* __restrict__ Wcd, const float* __restrict__ Wcn,
                             const float* __restrict__ Wnd, const float* __restrict__ Wn1,
                             const float* __restrict__ Wn2, const float* __restrict__ Wa0,
                             const float* __restrict__ Wa1, const float* __restrict__ Wn3,
                             unsigned short* __restrict__ WT) {
  int e = blockIdx.x * 256 + threadIdx.x;
  unsigned short r;
  if      (e < OFF_RD) r = convT<64, 128>(e - OFF_LD, Wld);
  else if (e < OFF_FD) r = convT<128, 768>(e - OFF_RD, Wrd);
  else if (e < OFF_C1) r = convT<256, 512>(e - OFF_FD, Wfd);
  else if (e < OFF_C2) r = convT<256, 256>(e - OFF_C1, Wc1);
  else if (e < OFF_C3) r = convT<256, 256>(e - OFF_C2, Wc2);
  else if (e < OFF_CD) r = convT<256, 256>(e - OFF_C3, Wc3);
  else if (e < OFF_CN) r = convT<256, 27>(e - OFF_CD, Wcd);
  else if (e < OFF_ND) r = convT<128, 256>(e - OFF_CN, Wcn);
  else if (e < OFF_N1) r = convT<256, 512>(e - OFF_ND, Wnd);
  else if (e < OFF_N2) r = convT<512, 512>(e - OFF_N1, Wn1);
  else if (e < OFF_A0) r = convT<512, 512>(e - OFF_N2, Wn2);
  else if (e < OFF_A1) r = convT<512, 1024>(e - OFF_A0, Wa0);
  else if (e < OFF_N3) r = convT<1024, 512>(e - OFF_A1, Wa1);
  else                 r = convT<512, 101>(e - OFF_N3, Wn3);
  WT[e] = r;
}

// Pipelined GEMM layer. A in XOR-swizzled LDS, B streamed from WT.
// PB = B-prefetch depth (k-steps); A prefetched 1 step ahead.
// ACT: 0=relu, 1=sigmoid(x), 2=sigmoid(2x).
template<int K, int NOUT, int GSIZE, int PB, int ACT, bool TO_GLOBAL, bool ADD>
__device__ __forceinline__ void layer(
    const unsigned short* __restrict__ Ain, int ars,
    const unsigned short* __restrict__ Bw,
    const float* __restrict__ bias,
    unsigned short* __restrict__ Lout, int ors,
    float* __restrict__ Gout, int gld,
    const unsigned short* __restrict__ Aadd, int rsa,
    int lane, int wid) {
  constexpr int NT = (NOUT + 15) >> 4;
  constexpr int NG = (NT + GSIZE - 1) / GSIZE;
  const int l15 = lane & 15;
  const int quad = lane >> 4;
  const int kh = quad << 3;
  const int sw = (l15 & 7) << 3;   // row&7 == l15&7 for rows m*16+l15
  for (int g = wid; g < NG; g += 8) {
    f32x4 acc[4][GSIZE] = {};
    const unsigned short* bp[GSIZE];
    int cols[GSIZE];
    #pragma unroll
    for (int t = 0; t < GSIZE; ++t) {
      int col = (g * GSIZE + t) * 16 + l15;
      cols[t] = col;
      int cc = col < NOUT ? col : NOUT - 1;   // clamp pad cols (safe dup work)
      bp[t] = Bw + (size_t)cc * K + kh;
    }
    const unsigned short* ap[4];
    #pragma unroll
    for (int m = 0; m < 4; ++m) ap[m] = Ain + (m * 16 + l15) * ars;
    // prologue
    bf16x8 bc[GSIZE], b1[GSIZE], ac[4];
    #pragma unroll
    for (int t = 0; t < GSIZE; ++t) bc[t] = *(const bf16x8*)(bp[t]);
    if constexpr (PB >= 2) {
      #pragma unroll
      for (int t = 0; t < GSIZE; ++t) b1[t] = *(const bf16x8*)(bp[t] + 32);
    }
    #pragma unroll
    for (int m = 0; m < 4; ++m) ac[m] = *(const bf16x8*)(ap[m] + (kh ^ sw));
    #pragma unroll
    for (int k0 = 0; k0 < K; k0 += 32) {
      bf16x8 bn[GSIZE], an[4];
      if (k0 + PB * 32 < K) {
        #pragma unroll
        for (int t = 0; t < GSIZE; ++t) bn[t] = *(const bf16x8*)(bp[t] + k0 + PB * 32);
      }
      if (k0 + 32 < K) {
        #pragma unroll
        for (int m = 0; m < 4; ++m) an[m] = *(const bf16x8*)(ap[m] + ((kh + k0 + 32) ^ sw));
      }
      #pragma unroll
      for (int m = 0; m < 4; ++m) {
        #pragma unroll
        for (int t = 0; t < GSIZE; ++t)
          acc[m][t] = __builtin_amdgcn_mfma_f32_16x16x32_bf16(ac[m], bc[t], acc[m][t], 0, 0, 0);
      }
      if (k0 + 32 < K) {
        #pragma unroll
        for (int m = 0; m < 4; ++m) ac[m] = an[m];
        if constexpr (PB >= 2) {
          #pragma unroll
          for (int t = 0; t < GSIZE; ++t) bc[t] = b1[t];
          if (k0 + 64 < K) {
            #pragma unroll
            for (int t = 0; t < GSIZE; ++t) b1[t] = bn[t];
          }
        } else {
          #pragma unroll
          for (int t = 0; t < GSIZE; ++t) bc[t] = bn[t];
        }
      }
    }
    // epilogue
    #pragma unroll
    for (int t = 0; t < GSIZE; ++t) {
      int cc = cols[t] < NOUT ? cols[t] : NOUT - 1;
      float bb = bias[cc];
      #pragma unroll
      for (int m = 0; m < 4; ++m) {
        #pragma unroll
        for (int j = 0; j < 4; ++j) {
          int row = m * 16 + quad * 4 + j;
          int rsw = (row & 7) << 3;
          float v = acc[m][t][j] + bb;
          if constexpr (ACT == 0) v = fmaxf(v, 0.f);
          else if constexpr (ACT == 1) v = 1.f / (1.f + __expf(-v));
          else if constexpr (ACT == 2) v = 1.f / (1.f + __expf(-2.f * v));
          if constexpr (ADD) v += b2f(Aadd[row * rsa + (cols[t] ^ rsw)]);
          if constexpr (TO_GLOBAL) {
            if (cols[t] < NOUT) Gout[(size_t)row * gld + cols[t]] = v;
          } else {
            Lout[row * ors + (cols[t] ^ rsw)] = f2b(v);
          }
        }
      }
    }
  }
}

// 512-wide relu layer, in-place on Wb, pipelined (PB=1). acc[4][4]=64 regs held
// until the barrier, then write-back. Row r's output depends only on row r's input.
template<int K>
__device__ __forceinline__ void layer512_ip(
    unsigned short* __restrict__ Wb,
    const unsigned short* __restrict__ Ain, int ars,
    const unsigned short* __restrict__ Bw, const float* __restrict__ bias,
    int lane, int wid) {
  const int l15 = lane & 15;
  const int quad = lane >> 4;
  const int kh = quad << 3;
  const int sw = (l15 & 7) << 3;
  f32x4 acc[4][4] = {};
  const unsigned short* bp[4];
  #pragma unroll
  for (int t = 0; t < 4; ++t)
    bp[t] = Bw + (size_t)(wid * 64 + t * 16 + l15) * K + kh;
  const unsigned short* ap[4];
  #pragma unroll
  for (int m = 0; m < 4; ++m) ap[m] = Ain + (m * 16 + l15) * ars;
  bf16x8 bc[4], ac[4];
  #pragma unroll
  for (int t = 0; t < 4; ++t) bc[t] = *(const bf16x8*)(bp[t]);
  #pragma unroll
  for (int m = 0; m < 4; ++m) ac[m] = *(const bf16x8*)(ap[m] + (kh ^ sw));
  #pragma unroll
  for (int k0 = 0; k0 < K; k0 += 32) {
    bf16x8 bn[4], an[4];
    if (k0 + 32 < K) {
      #pragma unroll
      for (int t = 0; t < 4; ++t) bn[t] = *(const bf16x8*)(bp[t] + k0 + 32);
      #pragma unroll
      for (int m = 0; m < 4; ++m) an[m] = *(const bf16x8*)(ap[m] + ((kh + k0 + 32) ^ sw));
    }
    #pragma unroll
    for (int m = 0; m < 4; ++m) {
      #pragma unroll
      for (int t = 0; t < 4; ++t)
        acc[m][t] = __builtin_amdgcn_mfma_f32_16x16x32_bf16(ac[m], bc[t], acc[m][t], 0, 0, 0);
    }
    if (k0 + 32 < K) {
      #pragma unroll
      for (int t = 0; t < 4; ++t) bc[t] = bn[t];
      #pragma unroll
      for (int m = 0; m < 4; ++m) ac[m] = an[m];
    }
  }
  __syncthreads();   // all reads of Wb done -> safe to overwrite
  #pragma unroll
  for (int t = 0; t < 4; ++t) {
    int col = wid * 64 + t * 16 + l15;
    float bb = bias[col];
    #pragma unroll
    for (int m = 0; m < 4; ++m) {
      #pragma unroll
      for (int j = 0; j < 4; ++j) {
        int row = m * 16 + quad * 4 + j;
        Wb[row * WRS + (col ^ ((row & 7) << 3))] = f2b(fmaxf(acc[m][t][j] + bb, 0.f));
      }
    }
  }
  __syncthreads();
}

// 512 threads, 80 KiB LDS -> 2 blocks/CU (16 waves = 4 waves/EU).
// amdgpu_waves_per_eu(4) pins the unified VGPR budget at 512/4 = 128/wave.
__global__ __attribute__((amdgpu_flat_work_group_size(512, 512)))
           __attribute__((amdgpu_waves_per_eu(4)))
void fused_vae(const float* __restrict__ z, const int* __restrict__ cind,
               const float* __restrict__ Emb,
               const float* __restrict__ bld, const float* __restrict__ brd,
               const float* __restrict__ bfd, const float* __restrict__ bc1,
               const float* __restrict__ bc2, const float* __restrict__ bc3,
               const float* __restrict__ bcd, const float* __restrict__ bcn,
               const float* __restrict__ bnd, const float* __restrict__ bn1,
               const float* __restrict__ bn2, const float* __restrict__ ba0,
               const float* __restrict__ ba1, const float* __restrict__ bn3,
               const unsigned short* __restrict__ WT, float* __restrict__ out) {
  __shared__ unsigned short lds[BM * (WRS + SRS)];   // 81,920 B
  unsigned short* Wb = lds;            // [64][512] swizzled
  unsigned short* Sb = lds + BM * WRS; // [64][128] swizzled
  const int tid = threadIdx.x;
  const int lane = tid & 63;
  const int wid = tid >> 6;
  const size_t row0 = (size_t)blockIdx.x * BM;

  // stage z -> Wb[:, 0:64] (swizzle XORs bits 3-5: stays within 0:64)
  for (int e = tid * 4; e < BM * 64; e += 512 * 4) {
    int r = e >> 6, c = e & 63;
    float4 v = *(const float4*)(z + (row0 + r) * 64 + c);
    ushort4 u; u.x = f2b(v.x); u.y = f2b(v.y); u.z = f2b(v.z); u.w = f2b(v.w);
    *(ushort4*)(&Wb[r * WRS + (c ^ ((r & 7) << 3))]) = u;
  }
  __syncthreads();
  // z1 = relu(z @ Wld + bld) -> Sb [64][128]
  layer<64, 128, 1, 2, 0, false, false>(Wb, WRS, WT + OFF_LD, bld, Sb, SRS, nullptr, 0, nullptr, 0, lane, wid);
  __syncthreads();
  // cl_h -> Wb[0:256]
  layer<128, 256, 2, 2, 0, false, false>(Sb, SRS, WT + OFF_RD + 512 * 128, brd + 512, Wb, WRS, nullptr, 0, nullptr, 0, lane, wid);
  __syncthreads();
  // c1 -> Wb[256:512] (ping-pong halves)
  layer<256, 256, 2, 2, 0, false, false>(Wb, WRS, WT + OFF_C1, bc1, Wb + 256, WRS, nullptr, 0, nullptr, 0, lane, wid);
  __syncthreads();
  layer<256, 256, 2, 2, 0, false, false>(Wb + 256, WRS, WT + OFF_C2, bc2, Wb, WRS, nullptr, 0, nullptr, 0, lane, wid);
  __syncthreads();
  layer<256, 256, 2, 2, 0, false, false>(Wb, WRS, WT + OFF_C3, bc3, Wb + 256, WRS, nullptr, 0, nullptr, 0, lane, wid);
  __syncthreads();
  // cluster -> global (reads Wb[256:512])  ||  feat_h -> Wb[0:256] (disjoint)
  layer<256, 27, 1, 2, 2, true, false>(Wb + 256, WRS, WT + OFF_CD, bcd, nullptr, 0,
                                       out + (size_t)NN * 613 + row0 * 27, 27, nullptr, 0, lane, wid);
  layer<128, 256, 2, 2, 0, false, false>(Sb, SRS, WT + OFF_RD, brd, Wb, WRS, nullptr, 0, nullptr, 0, lane, wid);
  __syncthreads();
  // feat -> global (reads Wb[0:256])  ||  nb_h -> Wb[256:512] (disjoint)
  layer<256, 512, 2, 2, 1, true, false>(Wb, WRS, WT + OFF_FD, bfd, nullptr, 0,
                                        out + row0 * 512, 512, nullptr, 0, lane, wid);
  layer<128, 256, 2, 2, 0, false, false>(Sb, SRS, WT + OFF_RD + 256 * 128, brd + 256, Wb + 256, WRS, nullptr, 0, nullptr, 0, lane, wid);
  __syncthreads();
  // stage emb -> Sb (z1 dead)
  for (int e = tid * 4; e < BM * 128; e += 512 * 4) {
    int r = e >> 7, c = e & 127;
    int ci = cind[row0 + r];
    float4 v = *(const float4*)(Emb + (size_t)ci * 128 + c);
    ushort4 u; u.x = f2b(v.x); u.y = f2b(v.y); u.z = f2b(v.z); u.w = f2b(v.w);
    *(ushort4*)(&Sb[r * SRS + (c ^ ((r & 7) << 3))]) = u;
  }
  __syncthreads();
  // x = relu(emb @ Wcn + bcn) + nb_h -> Wb[0:256] (ADD reads Wb[256:512], disjoint)
  layer<128, 256, 2, 2, 0, false, true>(Sb, SRS, WT + OFF_CN, bcn, Wb, WRS, nullptr, 0, Wb + 256, WRS, lane, wid);
  __syncthreads();
  // nf1..nf3: 512-wide, in-place through registers (pipelined)
  layer512_ip<256>(Wb, Wb, WRS, WT + OFF_ND, bnd, lane, wid);
  layer512_ip<512>(Wb, Wb, WRS, WT + OFF_N1, bn1, lane, wid);
  layer512_ip<512>(Wb, Wb, WRS, WT + OFF_N2, bn2, lane, wid);
  // a0 (1024-wide) in eight 128-col chunks through Sb, fused with a1 accumulation
  {
    const int l15 = lane & 15;
    const int quad = lane >> 4;
    const int kh = quad << 3;
    const int sw = (l15 & 7) << 3;
    f32x4 acc1[4][4] = {};
    const unsigned short* ap[4];
    #pragma unroll
    for (int m = 0; m < 4; ++m) ap[m] = Wb + (m * 16 + l15) * WRS;
    const unsigned short* sp[4];
    #pragma unroll
    for (int m = 0; m < 4; ++m) sp[m] = Sb + (m * 16 + l15) * SRS;
    #pragma unroll 1
    for (int e = 0; e < 8; ++e) {
      // a0 chunk: cols e*128..+127; each wave owns 16 cols (one per l15)
      f32x4 acc0[4] = {};
      const unsigned short* bp = WT + OFF_A0 + (size_t)(e * 128 + wid * 16 + l15) * 512 + kh;
      bf16x8 bc = *(const bf16x8*)(bp);
      #pragma unroll
      for (int k0 = 0; k0 < 512; k0 += 32) {
        bf16x8 bn;
        if (k0 + 32 < 512) bn = *(const bf16x8*)(bp + k0 + 32);
        #pragma unroll
        for (int m = 0; m < 4; ++m) {
          bf16x8 a = *(const bf16x8*)(ap[m] + ((kh + k0) ^ sw));
          acc0[m] = __builtin_amdgcn_mfma_f32_16x16x32_bf16(a, bc, acc0[m], 0, 0, 0);
        }
        if (k0 + 32 < 512) bc = bn;
      }
      __syncthreads();   // prev chunk's a1 reads of Sb done
      {
        int lc = wid * 16 + l15;
        float bb = ba0[e * 128 + lc];
        #pragma unroll
        for (int m = 0; m < 4; ++m) {
          #pragma unroll
          for (int j = 0; j < 4; ++j) {
            int row = m * 16 + quad * 4 + j;
            Sb[row * SRS + (lc ^ ((row & 7) << 3))] = f2b(fmaxf(acc0[m][j] + bb, 0.f));
          }
        }
      }
      __syncthreads();
      // a1 partial: K-chunk 128 from Sb
      const unsigned short* bp1[4];
      #pragma unroll
      for (int t = 0; t < 4; ++t)
        bp1[t] = WT + OFF_A1 + (size_t)(wid * 64 + t * 16 + l15) * 1024 + e * 128 + kh;
      #pragma unroll
      for (int k0 = 0; k0 < 128; k0 += 32) {
        bf16x8 b[4];
        #pragma unroll
        for (int t = 0; t < 4; ++t) b[t] = *(const bf16x8*)(bp1[t] + k0);
        #pragma unroll
        for (int m = 0; m < 4; ++m) {
          bf16x8 a = *(const bf16x8*)(sp[m] + ((kh + k0) ^ sw));
          #pragma unroll
          for (int t = 0; t < 4; ++t)
            acc1[m][t] = __builtin_amdgcn_mfma_f32_16x16x32_bf16(a, b[t], acc1[m][t], 0, 0, 0);
        }
      }
    }
    // a1 = relu(acc1 + ba1) -> Wb in place (all Wb reads finished before the
    // last chunk's Sb-write barrier)
    #pragma unroll
    for (int t = 0; t < 4; ++t) {
      int col = wid * 64 + t * 16 + l15;
      float bb = ba1[col];
      #pragma unroll
      for (int m = 0; m < 4; ++m) {
        #pragma unroll
        for (int j = 0; j < 4; ++j) {
          int row = m * 16 + quad * 4 + j;
          Wb[row * WRS + (col ^ ((row & 7) << 3))] = f2b(fmaxf(acc1[m][t][j] + bb, 0.f));
        }
      }
    }
  }
  __syncthreads();
  // neighbor_map = sigmoid(2*(a1 @ Wn3 + bn3)) -> global
  layer<512, 101, 1, 2, 2, true, false>(Wb, WRS, WT + OFF_N3, bn3, nullptr, 0,
                                        out + (size_t)NN * 512 + row0 * 101, 101, nullptr, 0, lane, wid);
}

extern "C" void kernel_launch(void* const* d_in, const int* in_sizes, int n_in,
                              void* d_out, int out_size, void* d_ws, size_t ws_size,
                              hipStream_t stream) {
  const float* z   = (const float*)d_in[0];
  const int*   cind= (const int*)d_in[1];
  const float* Emb = (const float*)d_in[2];
  const float* Wld = (const float*)d_in[3];  const float* bld = (const float*)d_in[4];
  const float* Wrd = (const float*)d_in[5];  const float* brd = (const float*)d_in[6];
  const float* Wfd = (const float*)d_in[7];  const float* bfd = (const float*)d_in[8];
  const float* Wc1 = (const float*)d_in[9];  const float* bc1 = (const float*)d_in[10];
  const float* Wc2 = (const float*)d_in[11]; const float* bc2 = (const float*)d_in[12];
  const float* Wc3 = (const float*)d_in[13]; const float* bc3 = (const float*)d_in[14];
  const float* Wcd = (const float*)d_in[15]; const float* bcd = (const float*)d_in[16];
  const float* Wcn = (const float*)d_in[17]; const float* bcn = (const float*)d_in[18];
  const float* Wnd = (const float*)d_in[19]; const float* bnd = (const float*)d_in[20];
  const float* Wn1 = (const float*)d_in[21]; const float* bn1 = (const float*)d_in[22];
  const float* Wn2 = (const float*)d_in[23]; const float* bn2 = (const float*)d_in[24];
  const float* Wa0 = (const float*)d_in[25]; const float* ba0 = (const float*)d_in[26];
  const float* Wa1 = (const float*)d_in[27]; const float* ba1 = (const float*)d_in[28];
  const float* Wn3 = (const float*)d_in[29]; const float* bn3 = (const float*)d_in[30];
  unsigned short* WT = (unsigned short*)d_ws;
  float* out = (float*)d_out;

  prep_weights<<<WT_TOTAL / 256, 256, 0, stream>>>(Wld, Wrd, Wfd, Wc1, Wc2, Wc3, Wcd,
                                                   Wcn, Wnd, Wn1, Wn2, Wa0, Wa1, Wn3, WT);
  fused_vae<<<NN / BM, 512, 0, stream>>>(z, cind, Emb, bld, brd, bfd, bc1, bc2, bc3,
                                         bcd, bcn, bnd, bn1, bn2, ba0, ba1, bn3, WT, out);
}

// Round 8
// 1161.800 us; speedup vs baseline: 2.0406x; 1.3269x over previous
//
#include <hip/hip_runtime.h>
#include <hip/hip_bf16.h>

typedef short bf16x8 __attribute__((ext_vector_type(8)));
typedef float f32x4 __attribute__((ext_vector_type(4)));

#define NN 131072
#define BM 64
#define LDW 520    // 512 + 8 pad cols (1040B row stride -> conflict-free ds_read_b128)
#define LDSS 136   // 128 + 8 pad cols

// WT (transposed bf16 weights) element offsets in d_ws
#define OFF_LD 0
#define OFF_RD 8192
#define OFF_FD 106496
#define OFF_C1 237568
#define OFF_C2 303104
#define OFF_C3 368640
#define OFF_CD 434176
#define OFF_CN 441088
#define OFF_ND 473856
#define OFF_N1 604928
#define OFF_N2 867072
#define OFF_A0 1129216
#define OFF_A1 1653504
#define OFF_N3 2177792
#define WT_TOTAL 2229504

__device__ __forceinline__ unsigned short f2b(float f) {
  __hip_bfloat16 h = __float2bfloat16(f);
  return __builtin_bit_cast(unsigned short, h);
}
__device__ __forceinline__ float b2f(unsigned short u) {
  return __bfloat162float(__builtin_bit_cast(__hip_bfloat16, u));
}

template<int Kd, int Md>
__device__ __forceinline__ unsigned short convT(int local, const float* __restrict__ W) {
  int mm = local / Kd;          // output col (row of WT)
  int kk = local - mm * Kd;     // k
  return f2b(W[(size_t)kk * Md + mm]);
}

__global__ void prep_weights(const float* __restrict__ Wld, const float* __restrict__ Wrd,
                             const float* __restrict__ Wfd, const float* __restrict__ Wc1,
                             const float* __restrict__ Wc2, const float* __restrict__ Wc3,
                             const float* __restrict__ Wcd, const float* __restrict__ Wcn,
                             const float* __restrict__ Wnd, const float* __restrict__ Wn1,
                             const float* __restrict__ Wn2, const float* __restrict__ Wa0,
                             const float* __restrict__ Wa1, const float* __restrict__ Wn3,
                             unsigned short* __restrict__ WT) {
  int e = blockIdx.x * 256 + threadIdx.x;
  unsigned short r;
  if      (e < OFF_RD) r = convT<64, 128>(e - OFF_LD, Wld);
  else if (e < OFF_FD) r = convT<128, 768>(e - OFF_RD, Wrd);
  else if (e < OFF_C1) r = convT<256, 512>(e - OFF_FD, Wfd);
  else if (e < OFF_C2) r = convT<256, 256>(e - OFF_C1, Wc1);
  else if (e < OFF_C3) r = convT<256, 256>(e - OFF_C2, Wc2);
  else if (e < OFF_CD) r = convT<256, 256>(e - OFF_C3, Wc3);
  else if (e < OFF_CN) r = convT<256, 27>(e - OFF_CD, Wcd);
  else if (e < OFF_ND) r = convT<128, 256>(e - OFF_CN, Wcn);
  else if (e < OFF_N1) r = convT<256, 512>(e - OFF_ND, Wnd);
  else if (e < OFF_N2) r = convT<512, 512>(e - OFF_N1, Wn1);
  else if (e < OFF_A0) r = convT<512, 512>(e - OFF_N2, Wn2);
  else if (e < OFF_A1) r = convT<512, 1024>(e - OFF_A0, Wa0);
  else if (e < OFF_N3) r = convT<1024, 512>(e - OFF_A1, Wa1);
  else                 r = convT<512, 101>(e - OFF_N3, Wn3);
  WT[e] = r;
}

// Deep-pipelined GEMM layer. A in padded LDS, B streamed from WT (L2/L3).
// Compile-time ring buffer of depth PB for B (indices constant-folded by the
// full unroll -> stays in registers), A double-buffered (depth 2).
// Slot reload happens after the MFMAs that consume it (WAR ordering), giving
// ~PB iterations of issue-to-use lookahead on the B stream.
// ACT: 0=relu, 1=sigmoid(x), 2=sigmoid(2x).
template<int K, int NOUT, int GSIZE, int PB, int ACT, bool TO_GLOBAL, bool ADD>
__device__ __forceinline__ void layer(
    const unsigned short* __restrict__ Ain, int lda,
    const unsigned short* __restrict__ Bw,
    const float* __restrict__ bias,
    unsigned short* __restrict__ Lout, int ldo,
    float* __restrict__ Gout, int gld,
    const unsigned short* __restrict__ Aadd, int ldadd,
    int lane, int wid) {
  constexpr int NS = K / 32;
  constexpr int NT = (NOUT + 15) >> 4;
  constexpr int NG = (NT + GSIZE - 1) / GSIZE;
  const int l15 = lane & 15;
  const int quad = lane >> 4;
  const int kh = quad << 3;
  for (int g = wid; g < NG; g += 8) {
    f32x4 acc[4][GSIZE] = {};
    const unsigned short* bp[GSIZE];
    int cols[GSIZE];
    #pragma unroll
    for (int t = 0; t < GSIZE; ++t) {
      int col = (g * GSIZE + t) * 16 + l15;
      cols[t] = col;
      int cc = col < NOUT ? col : NOUT - 1;   // clamp pad cols (safe dup work)
      bp[t] = Bw + (size_t)cc * K + kh;
    }
    const unsigned short* ap[4];
    #pragma unroll
    for (int m = 0; m < 4; ++m) ap[m] = Ain + (m * 16 + l15) * lda + kh;
    // prologue: fill B ring (depth PB) and A double-buffer
    bf16x8 bb[PB][GSIZE];
    bf16x8 aa[2][4];
    #pragma unroll
    for (int j = 0; j < PB; ++j) {
      if (j < NS) {
        #pragma unroll
        for (int t = 0; t < GSIZE; ++t) bb[j][t] = *(const bf16x8*)(bp[t] + j * 32);
      }
    }
    #pragma unroll
    for (int m = 0; m < 4; ++m) aa[0][m] = *(const bf16x8*)(ap[m]);
    if constexpr (NS > 1) {
      #pragma unroll
      for (int m = 0; m < 4; ++m) aa[1][m] = *(const bf16x8*)(ap[m] + 32);
    }
    #pragma unroll
    for (int s = 0; s < NS; ++s) {
      #pragma unroll
      for (int m = 0; m < 4; ++m) {
        #pragma unroll
        for (int t = 0; t < GSIZE; ++t)
          acc[m][t] = __builtin_amdgcn_mfma_f32_16x16x32_bf16(aa[s & 1][m], bb[s % PB][t], acc[m][t], 0, 0, 0);
      }
      if (s + PB < NS) {
        #pragma unroll
        for (int t = 0; t < GSIZE; ++t) bb[s % PB][t] = *(const bf16x8*)(bp[t] + (s + PB) * 32);
      }
      if (s + 2 < NS) {
        #pragma unroll
        for (int m = 0; m < 4; ++m) aa[s & 1][m] = *(const bf16x8*)(ap[m] + (s + 2) * 32);
      }
    }
    // epilogue
    #pragma unroll
    for (int t = 0; t < GSIZE; ++t) {
      int cc = cols[t] < NOUT ? cols[t] : NOUT - 1;
      float bb2 = bias[cc];
      #pragma unroll
      for (int m = 0; m < 4; ++m) {
        #pragma unroll
        for (int j = 0; j < 4; ++j) {
          int row = m * 16 + quad * 4 + j;
          float v = acc[m][t][j] + bb2;
          if constexpr (ACT == 0) v = fmaxf(v, 0.f);
          else if constexpr (ACT == 1) v = 1.f / (1.f + __expf(-v));
          else if constexpr (ACT == 2) v = 1.f / (1.f + __expf(-2.f * v));
          if constexpr (ADD) v += b2f(Aadd[row * ldadd + cols[t]]);
          if constexpr (TO_GLOBAL) {
            if (cols[t] < NOUT) Gout[(size_t)row * gld + cols[t]] = v;
          } else {
            Lout[row * ldo + cols[t]] = f2b(v);
          }
        }
      }
    }
  }
}

__global__ __launch_bounds__(512, 2)
void fused_vae(const float* __restrict__ z, const int* __restrict__ cind,
               const float* __restrict__ Emb,
               const float* __restrict__ bld, const float* __restrict__ brd,
               const float* __restrict__ bfd, const float* __restrict__ bc1,
               const float* __restrict__ bc2, const float* __restrict__ bc3,
               const float* __restrict__ bcd, const float* __restrict__ bcn,
               const float* __restrict__ bnd, const float* __restrict__ bn1,
               const float* __restrict__ bn2, const float* __restrict__ ba0,
               const float* __restrict__ ba1, const float* __restrict__ bn3,
               const unsigned short* __restrict__ WT, float* __restrict__ out) {
  __shared__ unsigned short sS[BM * LDSS];
  __shared__ unsigned short sA[BM * LDW];
  __shared__ unsigned short sB[BM * LDW];
  const int tid = threadIdx.x;
  const int lane = tid & 63;
  const int wid = tid >> 6;
  const size_t row0 = (size_t)blockIdx.x * BM;

  // stage z tile -> sA (bf16)
  for (int e = tid * 4; e < BM * 64; e += 512 * 4) {
    int r = e >> 6, c = e & 63;
    float4 v = *(const float4*)(z + (row0 + r) * 64 + c);
    ushort4 u; u.x = f2b(v.x); u.y = f2b(v.y); u.z = f2b(v.z); u.w = f2b(v.w);
    *(ushort4*)(&sA[r * LDW + c]) = u;
  }
  __syncthreads();
  // z1 = relu(z @ Wld + bld) -> sS [64][128]
  layer<64, 128, 1, 2, 0, false, false>(sA, LDW, WT + OFF_LD, bld, sS, LDSS, nullptr, 0, nullptr, 0, lane, wid);
  __syncthreads();
  // cl_h = relu(z1 @ Wrd[:,512:768] + brd[512:]) -> sB
  layer<128, 256, 2, 4, 0, false, false>(sS, LDSS, WT + OFF_RD + 512 * 128, brd + 512, sB, LDW, nullptr, 0, nullptr, 0, lane, wid);
  __syncthreads();
  layer<256, 256, 2, 4, 0, false, false>(sB, LDW, WT + OFF_C1, bc1, sA, LDW, nullptr, 0, nullptr, 0, lane, wid);
  __syncthreads();
  layer<256, 256, 2, 4, 0, false, false>(sA, LDW, WT + OFF_C2, bc2, sB, LDW, nullptr, 0, nullptr, 0, lane, wid);
  __syncthreads();
  layer<256, 256, 2, 4, 0, false, false>(sB, LDW, WT + OFF_C3, bc3, sA, LDW, nullptr, 0, nullptr, 0, lane, wid);
  __syncthreads();
  // cluster = sigmoid(2*(c3 @ Wcd + bcd)) -> global (waves 0-1)
  // || feat_h = relu(z1 @ Wrd[:,0:256]) -> sB (reads sS; disjoint from CD's sA)
  layer<256, 27, 1, 4, 2, true, false>(sA, LDW, WT + OFF_CD, bcd, nullptr, 0,
                                       out + (size_t)NN * 613 + row0 * 27, 27, nullptr, 0, lane, wid);
  layer<128, 256, 2, 4, 0, false, false>(sS, LDSS, WT + OFF_RD, brd, sB, LDW, nullptr, 0, nullptr, 0, lane, wid);
  __syncthreads();
  // feat = sigmoid(feat_h @ Wfd + bfd) -> global  ||  nb_h -> sA (reads sS)
  layer<256, 512, 4, 4, 1, true, false>(sB, LDW, WT + OFF_FD, bfd, nullptr, 0,
                                        out + row0 * 512, 512, nullptr, 0, lane, wid);
  layer<128, 256, 2, 4, 0, false, false>(sS, LDSS, WT + OFF_RD + 256 * 128, brd + 256, sA, LDW, nullptr, 0, nullptr, 0, lane, wid);
  __syncthreads();
  // stage emb = Emb[cluster_ind] -> sS (z1 dead)
  for (int e = tid * 4; e < BM * 128; e += 512 * 4) {
    int r = e >> 7, c = e & 127;
    int ci = cind[row0 + r];
    float4 v = *(const float4*)(Emb + (size_t)ci * 128 + c);
    ushort4 u; u.x = f2b(v.x); u.y = f2b(v.y); u.z = f2b(v.z); u.w = f2b(v.w);
    *(ushort4*)(&sS[r * LDSS + c]) = u;
  }
  __syncthreads();
  // x = relu(emb @ Wcn + bcn) + nb_h -> sB (ADD reads sA)
  layer<128, 256, 2, 4, 0, false, true>(sS, LDSS, WT + OFF_CN, bcn, sB, LDW, nullptr, 0, sA, LDW, lane, wid);
  __syncthreads();
  // nf1 -> sA
  layer<256, 512, 4, 4, 0, false, false>(sB, LDW, WT + OFF_ND, bnd, sA, LDW, nullptr, 0, nullptr, 0, lane, wid);
  __syncthreads();
  // nf2 -> sB
  layer<512, 512, 4, 4, 0, false, false>(sA, LDW, WT + OFF_N1, bn1, sB, LDW, nullptr, 0, nullptr, 0, lane, wid);
  __syncthreads();
  // nf3 -> sA
  layer<512, 512, 4, 4, 0, false, false>(sB, LDW, WT + OFF_N2, bn2, sA, LDW, nullptr, 0, nullptr, 0, lane, wid);
  __syncthreads();
  // a0 (1024-wide, two 512 halves through sB) fused with a1 accumulation in regs.
  // acc1 (64 regs) lives across the inner layer call -> PB=2 inside both phases.
  {
    const int l15 = lane & 15;
    const int quad = lane >> 4;
    const int kh = quad << 3;
    const int g = wid;            // each wave owns 64 cols of a1
    f32x4 acc1[4][4] = {};
    for (int h = 0; h < 2; ++h) {
      layer<512, 512, 4, 2, 0, false, false>(sA, LDW, WT + OFF_A0 + (size_t)h * 512 * 512,
                                             ba0 + h * 512, sB, LDW, nullptr, 0, nullptr, 0, lane, wid);
      __syncthreads();
      const unsigned short* wa1 = WT + OFF_A1 + h * 512;   // [512][1024], k-offset h*512
      const unsigned short* bp[4];
      #pragma unroll
      for (int t = 0; t < 4; ++t)
        bp[t] = wa1 + (size_t)(g * 64 + t * 16 + l15) * 1024 + kh;
      const unsigned short* ap[4];
      #pragma unroll
      for (int m = 0; m < 4; ++m) ap[m] = sB + (m * 16 + l15) * LDW + kh;
      // PB=2 ring pipeline over K=512 (16 steps)
      bf16x8 bb[2][4], aa[2][4];
      #pragma unroll
      for (int t = 0; t < 4; ++t) { bb[0][t] = *(const bf16x8*)(bp[t]); bb[1][t] = *(const bf16x8*)(bp[t] + 32); }
      #pragma unroll
      for (int m = 0; m < 4; ++m) { aa[0][m] = *(const bf16x8*)(ap[m]); aa[1][m] = *(const bf16x8*)(ap[m] + 32); }
      #pragma unroll
      for (int s = 0; s < 16; ++s) {
        #pragma unroll
        for (int m = 0; m < 4; ++m) {
          #pragma unroll
          for (int t = 0; t < 4; ++t)
            acc1[m][t] = __builtin_amdgcn_mfma_f32_16x16x32_bf16(aa[s & 1][m], bb[s & 1][t], acc1[m][t], 0, 0, 0);
        }
        if (s + 2 < 16) {
          #pragma unroll
          for (int t = 0; t < 4; ++t) bb[s & 1][t] = *(const bf16x8*)(bp[t] + (s + 2) * 32);
          #pragma unroll
          for (int m = 0; m < 4; ++m) aa[s & 1][m] = *(const bf16x8*)(ap[m] + (s + 2) * 32);
        }
      }
      __syncthreads();
    }
    // a1 = relu(acc1 + ba1) -> sB
    #pragma unroll
    for (int t = 0; t < 4; ++t) {
      int col = g * 64 + t * 16 + l15;
      float bb2 = ba1[col];
      #pragma unroll
      for (int m = 0; m < 4; ++m) {
        #pragma unroll
        for (int j = 0; j < 4; ++j) {
          int row = m * 16 + quad * 4 + j;
          sB[row * LDW + col] = f2b(fmaxf(acc1[m][t][j] + bb2, 0.f));
        }
      }
    }
  }
  __syncthreads();
  // neighbor_map = sigmoid(2*(a1 @ Wn3 + bn3)) -> global
  layer<512, 101, 1, 4, 2, true, false>(sB, LDW, WT + OFF_N3, bn3, nullptr, 0,
                                        out + (size_t)NN * 512 + row0 * 101, 101, nullptr, 0, lane, wid);
}

extern "C" void kernel_launch(void* const* d_in, const int* in_sizes, int n_in,
                              void* d_out, int out_size, void* d_ws, size_t ws_size,
                              hipStream_t stream) {
  const float* z   = (const float*)d_in[0];
  const int*   cind= (const int*)d_in[1];
  const float* Emb = (const float*)d_in[2];
  const float* Wld = (const float*)d_in[3];  const float* bld = (const float*)d_in[4];
  const float* Wrd = (const float*)d_in[5];  const float* brd = (const float*)d_in[6];
  const float* Wfd = (const float*)d_in[7];  const float* bfd = (const float*)d_in[8];
  const float* Wc1 = (const float*)d_in[9];  const float* bc1 = (const float*)d_in[10];
  const float* Wc2 = (const float*)d_in[11]; const float* bc2 = (const float*)d_in[12];
  const float* Wc3 = (const float*)d_in[13]; const float* bc3 = (const float*)d_in[14];
  const float* Wcd = (const float*)d_in[15]; const float* bcd = (const float*)d_in[16];
  const float* Wcn = (const float*)d_in[17]; const float* bcn = (const float*)d_in[18];
  const float* Wnd = (const float*)d_in[19]; const float* bnd = (const float*)d_in[20];
  const float* Wn1 = (const float*)d_in[21]; const float* bn1 = (const float*)d_in[22];
  const float* Wn2 = (const float*)d_in[23]; const float* bn2 = (const float*)d_in[24];
  const float* Wa0 = (const float*)d_in[25]; const float* ba0 = (const float*)d_in[26];
  const float* Wa1 = (const float*)d_in[27]; const float* ba1 = (const float*)d_in[28];
  const float* Wn3 = (const float*)d_in[29]; const float* bn3 = (const float*)d_in[30];
  unsigned short* WT = (unsigned short*)d_ws;
  float* out = (float*)d_out;

  prep_weights<<<WT_TOTAL / 256, 256, 0, stream>>>(Wld, Wrd, Wfd, Wc1, Wc2, Wc3, Wcd,
                                                   Wcn, Wnd, Wn1, Wn2, Wa0, Wa1, Wn3, WT);
  fused_vae<<<NN / BM, 512, 0, stream>>>(z, cind, Emb, bld, brd, bfd, bc1, bc2, bc3,
                                         bcd, bcn, bnd, bn1, bn2, ba0, ba1, bn3, WT, out);
}